// Round 10
// baseline (205.024 us; speedup 1.0000x reference)
//
#include <hip/hip_runtime.h>
#include <stdint.h>

// MoE: D=1024, N=8 experts, top-1 routed (0..6) + shared expert 7, gates == 1.0.
// Round 10: wcvt now reads W1 fully LINEARLY (8 full 16KB rows per block,
// LDS-staged bf16) and writes the packed k-slab tile image. zgemm2 stages B
// with contiguous 16KB global_load_lds tiles. Session-wide law: partial-row
// reads of 16KB-row W1 run at 1-2 TB/s; linear streaming runs at 6-7 TB/s.

typedef __bf16 bf16x8 __attribute__((ext_vector_type(8)));
typedef float f32x4 __attribute__((ext_vector_type(4)));

typedef __attribute__((address_space(1))) const void gvoid_t;
typedef __attribute__((address_space(3))) void lvoid_t;

__device__ __forceinline__ void gload16(void* lds, const void* g) {
  __builtin_amdgcn_global_load_lds((gvoid_t*)g, (lvoid_t*)lds, 16, 0, 0);
}

__device__ __forceinline__ uint16_t f2bf(float f) {
  union { float f; uint32_t u; } v; v.f = f;
  uint32_t u = v.u + 0x7fffu + ((v.u >> 16) & 1u);  // RNE
  return (uint16_t)(u >> 16);
}

#define S_VMCNT8()  asm volatile("s_waitcnt vmcnt(8)" ::: "memory")
#define S_VMCNT12() asm volatile("s_waitcnt vmcnt(12)" ::: "memory")
#define S_VMCNT16() asm volatile("s_waitcnt vmcnt(16)" ::: "memory")
#define S_VMCNT0()  asm volatile("s_waitcnt vmcnt(0)" ::: "memory")
#define S_LGKM0()   asm volatile("s_waitcnt lgkmcnt(0)" ::: "memory")
#define S_BAR()     __builtin_amdgcn_s_barrier()

#define CVT_PK(dst, lo, hi) \
  asm("v_cvt_pk_bf16_f32 %0, %1, %2" : "=v"(dst) : "v"(lo), "v"(hi))

// ---------------- gating + x->bf16 convert fused ----------------
__global__ __launch_bounds__(256) void gate_kernel(const float* __restrict__ x,
                                                   const float* __restrict__ Wg,
                                                   uint16_t* __restrict__ xbf,
                                                   int* __restrict__ idx) {
  int wid = threadIdx.x >> 6, lane = threadIdx.x & 63;
  int m = blockIdx.x * 4 + wid;
  const float* xr = x + (size_t)m * 1024;
  uint16_t* xbr = xbf + (size_t)m * 1024;
  float acc[8] = {0.f, 0.f, 0.f, 0.f, 0.f, 0.f, 0.f, 0.f};
  for (int it = 0; it < 4; ++it) {
    int dbase = it * 256 + lane * 4;
    float4 xv = *reinterpret_cast<const float4*>(xr + dbase);
    ushort4 o;
    o.x = f2bf(xv.x); o.y = f2bf(xv.y); o.z = f2bf(xv.z); o.w = f2bf(xv.w);
    *reinterpret_cast<ushort4*>(xbr + dbase) = o;
    const float* xp = reinterpret_cast<const float*>(&xv);
    for (int dd = 0; dd < 4; ++dd) {
      float xs = xp[dd];
      float4 w0 = *reinterpret_cast<const float4*>(Wg + (size_t)(dbase + dd) * 8);
      float4 w1 = *reinterpret_cast<const float4*>(Wg + (size_t)(dbase + dd) * 8 + 4);
      acc[0] += xs * w0.x; acc[1] += xs * w0.y; acc[2] += xs * w0.z; acc[3] += xs * w0.w;
      acc[4] += xs * w1.x; acc[5] += xs * w1.y; acc[6] += xs * w1.z; acc[7] += xs * w1.w;
    }
  }
  for (int j = 0; j < 7; ++j)
    for (int off = 32; off; off >>= 1)
      acc[j] += __shfl_xor(acc[j], off);
  if (lane == 0) {
    int best = 0; float bv = acc[0];
    for (int j = 1; j < 7; ++j) if (acc[j] > bv) { bv = acc[j]; best = j; }
    idx[m] = best;
  }
}

// -------- single-block stable counting sort --------
__global__ __launch_bounds__(256) void compact_kernel(const int* __restrict__ idx,
                                                      int* __restrict__ soff,
                                                      int* __restrict__ scnt,
                                                      int* __restrict__ rowmap,
                                                      int* __restrict__ tokrow) {
  __shared__ int hist[256][7];
  __shared__ int cnts[7];
  __shared__ int off[7];
  int t = threadIdx.x;
  int e8[8];
  int lh[7] = {0, 0, 0, 0, 0, 0, 0};
#pragma unroll
  for (int i = 0; i < 8; ++i) { int e = idx[t * 8 + i]; e8[i] = e; lh[e]++; }
#pragma unroll
  for (int e = 0; e < 7; ++e) hist[t][e] = lh[e];
  __syncthreads();
  if (t < 7) {
    int run = 0;
    for (int i = 0; i < 256; ++i) { int v = hist[i][t]; hist[i][t] = run; run += v; }
    cnts[t] = run;
  }
  __syncthreads();
  if (t == 0) {
    int run = 0;
    for (int e = 0; e < 7; ++e) { off[e] = run; soff[e] = run; scnt[e] = cnts[e]; run += cnts[e]; }
    soff[7] = 0; scnt[7] = 2048;
  }
  __syncthreads();
  int pos[7];
#pragma unroll
  for (int e = 0; e < 7; ++e) pos[e] = off[e] + hist[t][e];
#pragma unroll
  for (int i = 0; i < 8; ++i) {
    int m = t * 8 + i, e = e8[i];
    int r = pos[e]++;
    rowmap[r] = m;
    tokrow[m] = r;
  }
}

// ---------------- wcvt: W1 f32 -> packed slab image bf16, LINEAR reads ----------------
// Block b: e=b>>7, ro=b&127 -> rows ro*8..ro*8+7 (kt=ro>>3, kg=ro&7).
// Phase 1: stream 8 full 16KB rows sequentially into LDS (bf16).
// Phase 2: repack LDS -> tile(e,x,kt) slab kg: [swz(col) 128][ki 8].
__global__ __launch_bounds__(256) void wcvt_kernel(const float* __restrict__ W1,
                                                   uint16_t* __restrict__ w1p) {
  __shared__ uint16_t S[8][4096];   // 64 KB
  int b = blockIdx.x;
  int e = b >> 7, ro = b & 127;
  int kt = ro >> 3, kg = ro & 7;
  const float* src = W1 + ((size_t)e * 1024 + ro * 8) * 4096;
  int t = threadIdx.x;
#pragma unroll 1
  for (int r = 0; r < 8; ++r) {
    const float* rp = src + (size_t)r * 4096;
#pragma unroll
    for (int it = 0; it < 4; ++it) {
      int c = it * 1024 + t * 4;
      f32x4 v = *reinterpret_cast<const f32x4*>(rp + c);
      uint32_t q0, q1;
      CVT_PK(q0, v[0], v[1]);
      CVT_PK(q1, v[2], v[3]);
      uint2 u; u.x = q0; u.y = q1;
      *reinterpret_cast<uint2*>(&S[r][c]) = u;
    }
  }
  __syncthreads();
  uint16_t* base = w1p + (((size_t)(e * 32) * 16) + kt) * 8192 + kg * 1024;
#pragma unroll 1
  for (int p = 0; p < 16; ++p) {
    int o = p * 256 + t;
    int x = o >> 7, col = o & 127;
    int sw = col ^ ((col >> 2) & 7);
    int cg = x * 128 + col;
    uint16_t vals[8];
#pragma unroll
    for (int r = 0; r < 8; ++r) vals[r] = S[r][cg];
    uint16_t* dst = base + (size_t)x * (16 * 8192) + sw * 8;
    *reinterpret_cast<uint4*>(dst) = *reinterpret_cast<const uint4*>(vals);
  }
}

// ---------------- zgemm2: z = x @ W1 via packed B ----------------
// BM=128, BN=128, BK=64, NT=16, 256 thr, 64KB LDS dbuf, 2 blocks/CU.
// B staging: 4 linear gload16 of a contiguous 16KB tile. 8 VMEM/iter, vmcnt(8).
__global__ __launch_bounds__(256, 2) void zgemm2_kernel(
    const uint16_t* __restrict__ xbf,   // [2048][1024] bf16
    const uint16_t* __restrict__ w1p,   // packed slab image
    const int* __restrict__ soff, const int* __restrict__ scnt,
    const int* __restrict__ rowmap,
    uint16_t* __restrict__ za,          // [4096][2048] bf16
    uint16_t* __restrict__ zb)          // [4096][2048] bf16
{
  int by = blockIdx.y;
  int seg, rt;
  if (by < 42) { seg = by / 6; rt = by % 6; } else { seg = 7; rt = by - 42; }
  int cnt = scnt[seg];
  if (rt * 128 >= cnt) return;
  int base = (seg == 7) ? 2048 : soff[seg];
  int rbase = (seg == 7) ? 0 : soff[seg];
  int bx = blockIdx.x;
  uint16_t* zout = (bx < 16) ? za : zb;
  int zc0 = (bx < 16) ? bx * 128 : (bx - 16) * 128;

  __shared__ uint16_t lds[2][16384];  // A[128][64]@0 (16KB), B slab image @8192 (16KB)

  int t = threadIdx.x, lane = t & 63, w = t >> 6;
  int trow = w * 8 + ((t >> 3) & 7);
  int slot = (t & 7) ^ (trow & 7);

  const uint16_t* aptr[4];
#pragma unroll
  for (int i = 0; i < 4; ++i) {
    int rl = i * 32 + trow;
    int rr = rt * 128 + rl; if (rr >= cnt) rr = cnt - 1;
    int tok = (seg == 7) ? rr : rowmap[rbase + rr];
    aptr[i] = xbf + (size_t)tok * 1024 + slot * 8;
  }
  const uint16_t* bp = w1p + ((size_t)(seg * 32 + bx) * 16) * 8192 + t * 8;

  auto stage = [&](int buf, int kt) {
    uint16_t* L = lds[buf];
#pragma unroll
    for (int i = 0; i < 4; ++i) gload16(&L[(i * 32 + trow) * 64 + (t & 7) * 8], aptr[i] + kt * 64);
#pragma unroll
    for (int i = 0; i < 4; ++i) gload16(&L[8192 + i * 2048 + t * 8], bp + (size_t)kt * 8192 + i * 2048);
  };

  int wr = (w >> 1) & 1, wc = w & 1;
  int l15 = lane & 15, lk = lane >> 4;
  int boff[4];
#pragma unroll
  for (int n = 0; n < 4; ++n) {
    int cl = wc * 64 + n * 16 + l15;
    boff[n] = 8192 + (cl ^ ((cl >> 2) & 7)) * 8;
  }

  f32x4 acc[4][4] = {};

  auto compute = [&](int buf) {
    const uint16_t* L = lds[buf];
#pragma unroll
    for (int g = 0; g < 2; ++g) {
      __builtin_amdgcn_s_setprio(1);
      bf16x8 af[4];
#pragma unroll
      for (int m = 0; m < 4; ++m) {
        int row = wr * 64 + m * 16 + l15;
        int p = (g * 4 + lk) ^ (row & 7);
        af[m] = *reinterpret_cast<const bf16x8*>(&L[row * 64 + p * 8]);
      }
#pragma unroll
      for (int n = 0; n < 4; ++n) {
        bf16x8 bfr = *reinterpret_cast<const bf16x8*>(&L[boff[n] + (g * 4 + lk) * 1024]);
#pragma unroll
        for (int m = 0; m < 4; ++m)
          acc[m][n] = __builtin_amdgcn_mfma_f32_16x16x32_bf16(af[m], bfr, acc[m][n], 0, 0, 0);
      }
      __builtin_amdgcn_s_setprio(0);
    }
  };

  const int NT = 16;
  stage(0, 0);
  stage(1, 1);
#pragma unroll 1
  for (int kt = 0; kt < NT; ++kt) {
    if (kt < NT - 1) S_VMCNT8(); else S_VMCNT0();
    S_BAR();
    compute(kt & 1);
    S_BAR();
    if (kt < NT - 2) stage(kt & 1, kt + 2);
  }

#pragma unroll
  for (int m = 0; m < 4; ++m)
#pragma unroll
    for (int n = 0; n < 4; ++n) {
      int col = zc0 + wc * 64 + n * 16 + l15;
#pragma unroll
      for (int j = 0; j < 4; ++j) {
        int row = rt * 128 + wr * 64 + m * 16 + lk * 4 + j;
        if (row < cnt)
          zout[(size_t)(base + row) * 2048 + col] = f2bf(acc[m][n][j]);
      }
    }
}

// ---------------- swiglu: h = silu(zb) * za ----------------
__global__ __launch_bounds__(256) void swiglu_kernel(const uint16_t* __restrict__ za,
                                                     const uint16_t* __restrict__ zb,
                                                     uint16_t* __restrict__ h) {
  size_t base = (size_t)blockIdx.x * 2048 + threadIdx.x * 8;
  uint4 va = *reinterpret_cast<const uint4*>(za + base);
  uint4 vb = *reinterpret_cast<const uint4*>(zb + base);
  const uint16_t* pa = reinterpret_cast<const uint16_t*>(&va);
  const uint16_t* pb = reinterpret_cast<const uint16_t*>(&vb);
  uint16_t o[8];
#pragma unroll
  for (int i = 0; i < 8; ++i) {
    union { uint32_t u; float f; } a, b;
    a.u = (uint32_t)pa[i] << 16;
    b.u = (uint32_t)pb[i] << 16;
    float sv = b.f / (1.0f + __expf(-b.f));
    o[i] = f2bf(sv * a.f);
  }
  *reinterpret_cast<uint4*>(h + base) = *reinterpret_cast<uint4*>(o);
}

// ---------------- FFN2: compact rows @ W2 (natural f32) ----------------
__global__ __launch_bounds__(256, 2) void ffn2_kernel(
    const uint16_t* __restrict__ h,    // [4096][2048] bf16
    const float* __restrict__ W2,      // [8][2048][1024] f32 natural
    const int* __restrict__ soff, const int* __restrict__ scnt,
    float* __restrict__ y, float* __restrict__ yr)
{
  int by = blockIdx.y;
  int seg, rt;
  if (by < 42) { seg = by / 6; rt = by % 6; } else { seg = 7; rt = by - 42; }
  int cnt = scnt[seg];
  if (rt * 128 >= cnt) return;
  int base = (seg == 7) ? 2048 : soff[seg];
  int obase = (seg == 7) ? 0 : soff[seg];
  int n0 = blockIdx.x * 128;

  __shared__ uint16_t lds[2][16384];

  int t = threadIdx.x, lane = t & 63, w = t >> 6;
  int trow = w * 8 + ((t >> 3) & 7);
  int slot = (t & 7) ^ (trow & 7);

  const uint16_t* aptr[4];
#pragma unroll
  for (int i = 0; i < 4; ++i) {
    int rl = i * 32 + trow;
    int rr = rt * 128 + rl; if (rr >= cnt) rr = cnt - 1;
    aptr[i] = h + (size_t)(base + rr) * 2048 + slot * 8;
  }
  auto stageA = [&](int buf, int kt) {
    uint16_t* L = lds[buf];
#pragma unroll
    for (int i = 0; i < 4; ++i) gload16(&L[(i * 32 + trow) * 64 + (t & 7) * 8], aptr[i] + kt * 64);
  };

  const float* w2f = W2 + (size_t)seg * (2048u * 1024u);
  int kg = t >> 5;
  int n4 = (t & 31) * 4;
  const float* bsrc = w2f + (size_t)(kg * 8) * 1024 + n0 + n4;
  int bwoff[4];
#pragma unroll
  for (int j = 0; j < 4; ++j) {
    int cl = n4 + j;
    int sw = cl ^ ((cl >> 2) & 7);
    bwoff[j] = 8192 + kg * 1024 + sw * 8;
  }
  f32x4 P0[8], P1[8];
  auto issueB = [&](f32x4 (&P)[8], int kt) {
    const float* p = bsrc + (size_t)kt * 64 * 1024;
#pragma unroll
    for (int i = 0; i < 8; ++i) P[i] = *reinterpret_cast<const f32x4*>(p + (size_t)i * 1024);
  };
  auto writeB = [&](f32x4 (&P)[8], int buf) {
    uint16_t* L = lds[buf];
#pragma unroll
    for (int j = 0; j < 4; ++j) {
      uint32_t q0, q1, q2, q3;
      CVT_PK(q0, P[0][j], P[1][j]);
      CVT_PK(q1, P[2][j], P[3][j]);
      CVT_PK(q2, P[4][j], P[5][j]);
      CVT_PK(q3, P[6][j], P[7][j]);
      uint4 v; v.x = q0; v.y = q1; v.z = q2; v.w = q3;
      *reinterpret_cast<uint4*>(&L[bwoff[j]]) = v;
    }
  };

  int wr = (w >> 1) & 1, wc = w & 1;
  int l15 = lane & 15, lk = lane >> 4;
  int boff[4];
#pragma unroll
  for (int n = 0; n < 4; ++n) {
    int cl = wc * 64 + n * 16 + l15;
    boff[n] = 8192 + (cl ^ ((cl >> 2) & 7)) * 8;
  }

  f32x4 acc[4][4] = {};

  auto compute = [&](int buf) {
    const uint16_t* L = lds[buf];
#pragma unroll
    for (int g = 0; g < 2; ++g) {
      __builtin_amdgcn_s_setprio(1);
      bf16x8 af[4];
#pragma unroll
      for (int m = 0; m < 4; ++m) {
        int row = wr * 64 + m * 16 + l15;
        int p = (g * 4 + lk) ^ (row & 7);
        af[m] = *reinterpret_cast<const bf16x8*>(&L[row * 64 + p * 8]);
      }
#pragma unroll
      for (int n = 0; n < 4; ++n) {
        bf16x8 bfr = *reinterpret_cast<const bf16x8*>(&L[boff[n] + (g * 4 + lk) * 1024]);
#pragma unroll
        for (int m = 0; m < 4; ++m)
          acc[m][n] = __builtin_amdgcn_mfma_f32_16x16x32_bf16(af[m], bfr, acc[m][n], 0, 0, 0);
      }
      __builtin_amdgcn_s_setprio(0);
    }
  };

  const int NT = 32;
  issueB(P0, 0); stageA(0, 0);
  issueB(P1, 1); stageA(1, 1);
  S_VMCNT16();
  writeB(P0, 0);
  issueB(P0, 2);
  S_LGKM0();

#pragma unroll 1
  for (int kt = 0; kt < NT; kt += 2) {
    if (kt < NT - 2) S_VMCNT12(); else S_VMCNT0();
    S_BAR();
    compute(0);
    if (kt < NT - 1) writeB(P1, 1);
    S_LGKM0(); S_BAR();
    if (kt < NT - 3) issueB(P1, kt + 3);
    if (kt < NT - 2) stageA(0, kt + 2);
    int ko = kt + 1;
    if (ko < NT - 2) S_VMCNT12(); else S_VMCNT0();
    S_BAR();
    compute(1);
    if (ko < NT - 1) writeB(P0, 0);
    S_LGKM0(); S_BAR();
    if (ko < NT - 3) issueB(P0, ko + 3);
    if (ko < NT - 2) stageA(1, ko + 2);
  }

#pragma unroll
  for (int m = 0; m < 4; ++m)
#pragma unroll
    for (int n = 0; n < 4; ++n) {
      int col = n0 + wc * 64 + n * 16 + l15;
#pragma unroll
      for (int j = 0; j < 4; ++j) {
        int row = rt * 128 + wr * 64 + m * 16 + lk * 4 + j;
        if (row < cnt) {
          if (seg == 7) y[(size_t)row * 1024 + col] = acc[m][n][j];
          else          yr[(size_t)(obase + row) * 1024 + col] = acc[m][n][j];
        }
      }
    }
}

// ---------------- combine: y[m] += yr[tokrow[m]] ----------------
__global__ __launch_bounds__(256) void combine_kernel(const float* __restrict__ yr,
                                                      const int* __restrict__ tokrow,
                                                      float* __restrict__ y) {
  int m = blockIdx.x;
  int d = threadIdx.x * 4;
  int r = tokrow[m];
  float4 a = *reinterpret_cast<const float4*>(yr + (size_t)r * 1024 + d);
  float4 o = *reinterpret_cast<const float4*>(y + (size_t)m * 1024 + d);
  o.x += a.x; o.y += a.y; o.z += a.z; o.w += a.w;
  *reinterpret_cast<float4*>(y + (size_t)m * 1024 + d) = o;
}

extern "C" void kernel_launch(void* const* d_in, const int* in_sizes, int n_in,
                              void* d_out, int out_size, void* d_ws, size_t ws_size,
                              hipStream_t stream)
{
  const float* x   = (const float*)d_in[0];   // [2048][1024]
  const float* Wg  = (const float*)d_in[1];   // [1024][8]
  const float* Wl1 = (const float*)d_in[2];   // [8][1024][4096]
  const float* Wl2 = (const float*)d_in[3];   // [8][2048][1024]
  float* y = (float*)d_out;                   // [2048][1024]
  char* ws = (char*)d_ws;

  uint16_t* xbf = (uint16_t*)(ws);                    //  4 MiB
  uint16_t* h   = (uint16_t*)(ws + (4ull  << 20));    // 16 MiB
  float*    yr  = (float*)   (ws + (20ull << 20));    //  8 MiB
  uint16_t* za  = (uint16_t*)(ws + (28ull << 20));    // 16 MiB
  uint16_t* zb  = (uint16_t*)(ws + (44ull << 20));    // 16 MiB
  uint16_t* w1p = (uint16_t*)(ws + (60ull << 20));    // 64 MiB
  int* idx    = (int*)(ws + (124ull << 20));
  int* tokrow = idx + 2048;
  int* soff   = tokrow + 2048;
  int* scnt   = soff + 8;
  int* rowmap = scnt + 8;  // 2048 ints

  gate_kernel<<<512, 256, 0, stream>>>(x, Wg, xbf, idx);
  compact_kernel<<<1, 256, 0, stream>>>(idx, soff, scnt, rowmap, tokrow);
  wcvt_kernel<<<1024, 256, 0, stream>>>(Wl1, w1p);
  zgemm2_kernel<<<dim3(32, 58), 256, 0, stream>>>(xbf, w1p, soff, scnt, rowmap, za, zb);
  swiglu_kernel<<<4096, 256, 0, stream>>>(za, zb, h);
  ffn2_kernel<<<dim3(8, 58), 256, 0, stream>>>(h, Wl2, soff, scnt, y, yr);
  combine_kernel<<<2048, 256, 0, stream>>>(yr, tokrow, y);
}

// Round 11
// 131.056 us; speedup vs baseline: 1.5644x; 1.5644x over previous
//
#include <hip/hip_runtime.h>
#include <stdint.h>

// MoE: D=1024, N=8 experts, top-1 routed (0..6) + shared expert 7, gates == 1.0.
// Round 11: r6 pipeline, but ffn1's B-read is remapped to 4x32-col chunks, one
// per 4KB quarter of the 16KB W1 row (cols g*1024 + bx*32 + j, g=0..3). This
// varies DRAM-channel address bits (12:13) across each block's k-row reads --
// the property that makes ffn2's 4KB-row W2 reads run at the HBM roof.
// Quarters 0,1 = a-half, 2,3 = paired b-half (2048+col) -> SwiGLU stays fused.

typedef __bf16 bf16x8 __attribute__((ext_vector_type(8)));
typedef float f32x4 __attribute__((ext_vector_type(4)));

typedef __attribute__((address_space(1))) const void gvoid_t;
typedef __attribute__((address_space(3))) void lvoid_t;

__device__ __forceinline__ void gload16(void* lds, const void* g) {
  __builtin_amdgcn_global_load_lds((gvoid_t*)g, (lvoid_t*)lds, 16, 0, 0);
}

__device__ __forceinline__ uint16_t f2bf(float f) {
  union { float f; uint32_t u; } v; v.f = f;
  uint32_t u = v.u + 0x7fffu + ((v.u >> 16) & 1u);  // RNE
  return (uint16_t)(u >> 16);
}

#define S_VMCNT12() asm volatile("s_waitcnt vmcnt(12)" ::: "memory")
#define S_VMCNT16() asm volatile("s_waitcnt vmcnt(16)" ::: "memory")
#define S_VMCNT0()  asm volatile("s_waitcnt vmcnt(0)" ::: "memory")
#define S_LGKM0()   asm volatile("s_waitcnt lgkmcnt(0)" ::: "memory")
#define S_BAR()     __builtin_amdgcn_s_barrier()

#define CVT_PK(dst, lo, hi) \
  asm("v_cvt_pk_bf16_f32 %0, %1, %2" : "=v"(dst) : "v"(lo), "v"(hi))

// ---------------- gating + x->bf16 convert fused ----------------
__global__ __launch_bounds__(256) void gate_kernel(const float* __restrict__ x,
                                                   const float* __restrict__ Wg,
                                                   uint16_t* __restrict__ xbf,
                                                   int* __restrict__ idx) {
  int wid = threadIdx.x >> 6, lane = threadIdx.x & 63;
  int m = blockIdx.x * 4 + wid;
  const float* xr = x + (size_t)m * 1024;
  uint16_t* xbr = xbf + (size_t)m * 1024;
  float acc[8] = {0.f, 0.f, 0.f, 0.f, 0.f, 0.f, 0.f, 0.f};
  for (int it = 0; it < 4; ++it) {
    int dbase = it * 256 + lane * 4;
    float4 xv = *reinterpret_cast<const float4*>(xr + dbase);
    ushort4 o;
    o.x = f2bf(xv.x); o.y = f2bf(xv.y); o.z = f2bf(xv.z); o.w = f2bf(xv.w);
    *reinterpret_cast<ushort4*>(xbr + dbase) = o;
    const float* xp = reinterpret_cast<const float*>(&xv);
    for (int dd = 0; dd < 4; ++dd) {
      float xs = xp[dd];
      float4 w0 = *reinterpret_cast<const float4*>(Wg + (size_t)(dbase + dd) * 8);
      float4 w1 = *reinterpret_cast<const float4*>(Wg + (size_t)(dbase + dd) * 8 + 4);
      acc[0] += xs * w0.x; acc[1] += xs * w0.y; acc[2] += xs * w0.z; acc[3] += xs * w0.w;
      acc[4] += xs * w1.x; acc[5] += xs * w1.y; acc[6] += xs * w1.z; acc[7] += xs * w1.w;
    }
  }
  for (int j = 0; j < 7; ++j)
    for (int off = 32; off; off >>= 1)
      acc[j] += __shfl_xor(acc[j], off);
  if (lane == 0) {
    int best = 0; float bv = acc[0];
    for (int j = 1; j < 7; ++j) if (acc[j] > bv) { bv = acc[j]; best = j; }
    idx[m] = best;
  }
}

// -------- single-block stable counting sort --------
__global__ __launch_bounds__(256) void compact_kernel(const int* __restrict__ idx,
                                                      int* __restrict__ soff,
                                                      int* __restrict__ scnt,
                                                      int* __restrict__ rowmap,
                                                      int* __restrict__ tokrow) {
  __shared__ int hist[256][7];
  __shared__ int cnts[7];
  __shared__ int off[7];
  int t = threadIdx.x;
  int e8[8];
  int lh[7] = {0, 0, 0, 0, 0, 0, 0};
#pragma unroll
  for (int i = 0; i < 8; ++i) { int e = idx[t * 8 + i]; e8[i] = e; lh[e]++; }
#pragma unroll
  for (int e = 0; e < 7; ++e) hist[t][e] = lh[e];
  __syncthreads();
  if (t < 7) {
    int run = 0;
    for (int i = 0; i < 256; ++i) { int v = hist[i][t]; hist[i][t] = run; run += v; }
    cnts[t] = run;
  }
  __syncthreads();
  if (t == 0) {
    int run = 0;
    for (int e = 0; e < 7; ++e) { off[e] = run; soff[e] = run; scnt[e] = cnts[e]; run += cnts[e]; }
    soff[7] = 0; scnt[7] = 2048;
  }
  __syncthreads();
  int pos[7];
#pragma unroll
  for (int e = 0; e < 7; ++e) pos[e] = off[e] + hist[t][e];
#pragma unroll
  for (int i = 0; i < 8; ++i) {
    int m = t * 8 + i, e = e8[i];
    int r = pos[e]++;
    rowmap[r] = m;
    tokrow[m] = r;
  }
}

// ---------------- FFN1: h = silu(x@W1_b) * (x@W1_a), W1 natural f32 ----------------
// BM=128, BK=64. Block bx (0..31) owns cols {g*1024 + bx*32 + j : g=0..3, j=0..31}.
// LDS B cols 0..63 = quarters 0,1 (a-half); 64..127 = quarters 2,3 (b-half).
// B reg-staged (2 sets, dist 2) f32->bf16, counted vmcnt(12).
__global__ __launch_bounds__(256, 2) void ffn1_kernel(
    const uint16_t* __restrict__ xbf,   // [2048][1024] bf16
    const float* __restrict__ W1,       // [8][1024][4096] f32 natural
    const int* __restrict__ soff, const int* __restrict__ scnt,
    const int* __restrict__ rowmap,
    uint16_t* __restrict__ h)           // [4096 compact rows][2048] bf16
{
  int by = blockIdx.y;
  int seg, rt;
  if (by < 42) { seg = by / 6; rt = by % 6; } else { seg = 7; rt = by - 42; }
  int cnt = scnt[seg];
  if (rt * 128 >= cnt) return;
  int base = (seg == 7) ? 2048 : soff[seg];
  int rbase = (seg == 7) ? 0 : soff[seg];
  int bx = blockIdx.x;

  __shared__ uint16_t lds[2][16384];  // A[128][64]@0 (16KB), B 8 k-slabs @8192 (16KB)

  int t = threadIdx.x, lane = t & 63, w = t >> 6;
  int trow = w * 8 + ((t >> 3) & 7);
  int slot = (t & 7) ^ (trow & 7);

  // ---- A staging (bf16 gload_lds) ----
  const uint16_t* aptr[4];
#pragma unroll
  for (int i = 0; i < 4; ++i) {
    int rl = i * 32 + trow;
    int rr = rt * 128 + rl; if (rr >= cnt) rr = cnt - 1;
    int tok = (seg == 7) ? rr : rowmap[rbase + rr];
    aptr[i] = xbf + (size_t)tok * 1024 + slot * 8;
  }
  auto stageA = [&](int buf, int kt) {
    uint16_t* L = lds[buf];
#pragma unroll
    for (int i = 0; i < 4; ++i) gload16(&L[(i * 32 + trow) * 64 + (t & 7) * 8], aptr[i] + kt * 64);
  };

  // ---- B staging: 4-quarter column mapping (channel-spread) ----
  const float* w1f = W1 + (size_t)seg * (1024u * 4096u);
  int kg = t >> 5;
  int n4 = (t & 31) * 4;                      // LDS col 0..124
  int gcol = (n4 >> 5) * 1024 + bx * 32 + (n4 & 31);   // quarter*(1024) + chunk
  const float* bsrc = w1f + (size_t)(kg * 8) * 4096 + gcol;
  int bwoff[4];
#pragma unroll
  for (int j = 0; j < 4; ++j) {
    int cl = n4 + j;
    int sw = cl ^ ((cl >> 2) & 7);
    bwoff[j] = 8192 + kg * 1024 + sw * 8;
  }
  f32x4 P0[8], P1[8];
  auto issueB = [&](f32x4 (&P)[8], int kt) {
    const float* p = bsrc + (size_t)kt * 64 * 4096;
#pragma unroll
    for (int i = 0; i < 8; ++i) P[i] = *reinterpret_cast<const f32x4*>(p + (size_t)i * 4096);
  };
  auto writeB = [&](f32x4 (&P)[8], int buf) {
    uint16_t* L = lds[buf];
#pragma unroll
    for (int j = 0; j < 4; ++j) {
      uint32_t q0, q1, q2, q3;
      CVT_PK(q0, P[0][j], P[1][j]);
      CVT_PK(q1, P[2][j], P[3][j]);
      CVT_PK(q2, P[4][j], P[5][j]);
      CVT_PK(q3, P[6][j], P[7][j]);
      uint4 v; v.x = q0; v.y = q1; v.z = q2; v.w = q3;
      *reinterpret_cast<uint4*>(&L[bwoff[j]]) = v;
    }
  };

  int wr = (w >> 1) & 1, wc = w & 1;
  int l15 = lane & 15, lk = lane >> 4;
  int boffA[2], boffB[2];
#pragma unroll
  for (int n = 0; n < 2; ++n) {
    int cl = wc * 32 + n * 16 + l15;          // LDS a-col 0..63
    boffA[n] = 8192 + (cl ^ ((cl >> 2) & 7)) * 8;
    int cb = cl + 64;                         // LDS b-col 64..127
    boffB[n] = 8192 + (cb ^ ((cb >> 2) & 7)) * 8;
  }

  f32x4 acca[4][2] = {};
  f32x4 accb[4][2] = {};

  auto compute = [&](int buf) {
    const uint16_t* L = lds[buf];
#pragma unroll
    for (int g = 0; g < 2; ++g) {
      __builtin_amdgcn_s_setprio(1);
      bf16x8 af[4];
#pragma unroll
      for (int m = 0; m < 4; ++m) {
        int row = wr * 64 + m * 16 + l15;
        int p = (g * 4 + lk) ^ (row & 7);
        af[m] = *reinterpret_cast<const bf16x8*>(&L[row * 64 + p * 8]);
      }
#pragma unroll
      for (int n = 0; n < 2; ++n) {
        int ks = (g * 4 + lk) * 1024;
        bf16x8 ba = *reinterpret_cast<const bf16x8*>(&L[boffA[n] + ks]);
        bf16x8 bb = *reinterpret_cast<const bf16x8*>(&L[boffB[n] + ks]);
#pragma unroll
        for (int m = 0; m < 4; ++m) {
          acca[m][n] = __builtin_amdgcn_mfma_f32_16x16x32_bf16(af[m], ba, acca[m][n], 0, 0, 0);
          accb[m][n] = __builtin_amdgcn_mfma_f32_16x16x32_bf16(af[m], bb, accb[m][n], 0, 0, 0);
        }
      }
      __builtin_amdgcn_s_setprio(0);
    }
  };

  const int NT = 16;
  issueB(P0, 0); stageA(0, 0);
  issueB(P1, 1); stageA(1, 1);
  S_VMCNT16();
  writeB(P0, 0);
  issueB(P0, 2);
  S_LGKM0();

#pragma unroll 1
  for (int kt = 0; kt < NT; kt += 2) {
    if (kt < NT - 2) S_VMCNT12(); else S_VMCNT0();
    S_BAR();
    compute(0);
    if (kt < NT - 1) writeB(P1, 1);
    S_LGKM0(); S_BAR();
    if (kt < NT - 3) issueB(P1, kt + 3);
    if (kt < NT - 2) stageA(0, kt + 2);
    int ko = kt + 1;
    if (ko < NT - 2) S_VMCNT12(); else S_VMCNT0();
    S_BAR();
    compute(1);
    if (ko < NT - 1) writeB(P0, 0);
    S_LGKM0(); S_BAR();
    if (ko < NT - 3) issueB(P0, ko + 3);
    if (ko < NT - 2) stageA(1, ko + 2);
  }

#pragma unroll
  for (int m = 0; m < 4; ++m)
#pragma unroll
    for (int n = 0; n < 2; ++n) {
      int cl = wc * 32 + n * 16 + l15;                       // LDS a-col 0..63
      int col = (cl >> 5) * 1024 + bx * 32 + (cl & 31);      // global h col
#pragma unroll
      for (int j = 0; j < 4; ++j) {
        int row = rt * 128 + wr * 64 + m * 16 + lk * 4 + j;
        if (row < cnt) {
          float a = acca[m][n][j], b = accb[m][n][j];
          float sv = b / (1.0f + __expf(-b));
          h[(size_t)(base + row) * 2048 + col] = f2bf(sv * a);
        }
      }
    }
}

// ---------------- FFN2: compact rows @ W2 (natural f32); shared->y, routed->yr ----------------
// BM=128, BN=128, BK=64, NT=32, 256 thr. Proven ~roof; unchanged from r6.
__global__ __launch_bounds__(256, 2) void ffn2_kernel(
    const uint16_t* __restrict__ h,    // [4096][2048] bf16
    const float* __restrict__ W2,      // [8][2048][1024] f32 natural
    const int* __restrict__ soff, const int* __restrict__ scnt,
    float* __restrict__ y, float* __restrict__ yr)
{
  int by = blockIdx.y;
  int seg, rt;
  if (by < 42) { seg = by / 6; rt = by % 6; } else { seg = 7; rt = by - 42; }
  int cnt = scnt[seg];
  if (rt * 128 >= cnt) return;
  int base = (seg == 7) ? 2048 : soff[seg];
  int obase = (seg == 7) ? 0 : soff[seg];
  int n0 = blockIdx.x * 128;

  __shared__ uint16_t lds[2][16384];

  int t = threadIdx.x, lane = t & 63, w = t >> 6;
  int trow = w * 8 + ((t >> 3) & 7);
  int slot = (t & 7) ^ (trow & 7);

  const uint16_t* aptr[4];
#pragma unroll
  for (int i = 0; i < 4; ++i) {
    int rl = i * 32 + trow;
    int rr = rt * 128 + rl; if (rr >= cnt) rr = cnt - 1;
    aptr[i] = h + (size_t)(base + rr) * 2048 + slot * 8;
  }
  auto stageA = [&](int buf, int kt) {
    uint16_t* L = lds[buf];
#pragma unroll
    for (int i = 0; i < 4; ++i) gload16(&L[(i * 32 + trow) * 64 + (t & 7) * 8], aptr[i] + kt * 64);
  };

  const float* w2f = W2 + (size_t)seg * (2048u * 1024u);
  int kg = t >> 5;
  int n4 = (t & 31) * 4;
  const float* bsrc = w2f + (size_t)(kg * 8) * 1024 + n0 + n4;
  int bwoff[4];
#pragma unroll
  for (int j = 0; j < 4; ++j) {
    int cl = n4 + j;
    int sw = cl ^ ((cl >> 2) & 7);
    bwoff[j] = 8192 + kg * 1024 + sw * 8;
  }
  f32x4 P0[8], P1[8];
  auto issueB = [&](f32x4 (&P)[8], int kt) {
    const float* p = bsrc + (size_t)kt * 64 * 1024;
#pragma unroll
    for (int i = 0; i < 8; ++i) P[i] = *reinterpret_cast<const f32x4*>(p + (size_t)i * 1024);
  };
  auto writeB = [&](f32x4 (&P)[8], int buf) {
    uint16_t* L = lds[buf];
#pragma unroll
    for (int j = 0; j < 4; ++j) {
      uint32_t q0, q1, q2, q3;
      CVT_PK(q0, P[0][j], P[1][j]);
      CVT_PK(q1, P[2][j], P[3][j]);
      CVT_PK(q2, P[4][j], P[5][j]);
      CVT_PK(q3, P[6][j], P[7][j]);
      uint4 v; v.x = q0; v.y = q1; v.z = q2; v.w = q3;
      *reinterpret_cast<uint4*>(&L[bwoff[j]]) = v;
    }
  };

  int wr = (w >> 1) & 1, wc = w & 1;
  int l15 = lane & 15, lk = lane >> 4;
  int boff[4];
#pragma unroll
  for (int n = 0; n < 4; ++n) {
    int cl = wc * 64 + n * 16 + l15;
    boff[n] = 8192 + (cl ^ ((cl >> 2) & 7)) * 8;
  }

  f32x4 acc[4][4] = {};

  auto compute = [&](int buf) {
    const uint16_t* L = lds[buf];
#pragma unroll
    for (int g = 0; g < 2; ++g) {
      __builtin_amdgcn_s_setprio(1);
      bf16x8 af[4];
#pragma unroll
      for (int m = 0; m < 4; ++m) {
        int row = wr * 64 + m * 16 + l15;
        int p = (g * 4 + lk) ^ (row & 7);
        af[m] = *reinterpret_cast<const bf16x8*>(&L[row * 64 + p * 8]);
      }
#pragma unroll
      for (int n = 0; n < 4; ++n) {
        bf16x8 bfr = *reinterpret_cast<const bf16x8*>(&L[boff[n] + (g * 4 + lk) * 1024]);
#pragma unroll
        for (int m = 0; m < 4; ++m)
          acc[m][n] = __builtin_amdgcn_mfma_f32_16x16x32_bf16(af[m], bfr, acc[m][n], 0, 0, 0);
      }
      __builtin_amdgcn_s_setprio(0);
    }
  };

  const int NT = 32;
  issueB(P0, 0); stageA(0, 0);
  issueB(P1, 1); stageA(1, 1);
  S_VMCNT16();
  writeB(P0, 0);
  issueB(P0, 2);
  S_LGKM0();

#pragma unroll 1
  for (int kt = 0; kt < NT; kt += 2) {
    if (kt < NT - 2) S_VMCNT12(); else S_VMCNT0();
    S_BAR();
    compute(0);
    if (kt < NT - 1) writeB(P1, 1);
    S_LGKM0(); S_BAR();
    if (kt < NT - 3) issueB(P1, kt + 3);
    if (kt < NT - 2) stageA(0, kt + 2);
    int ko = kt + 1;
    if (ko < NT - 2) S_VMCNT12(); else S_VMCNT0();
    S_BAR();
    compute(1);
    if (ko < NT - 1) writeB(P0, 0);
    S_LGKM0(); S_BAR();
    if (ko < NT - 3) issueB(P0, ko + 3);
    if (ko < NT - 2) stageA(1, ko + 2);
  }

#pragma unroll
  for (int m = 0; m < 4; ++m)
#pragma unroll
    for (int n = 0; n < 4; ++n) {
      int col = n0 + wc * 64 + n * 16 + l15;
#pragma unroll
      for (int j = 0; j < 4; ++j) {
        int row = rt * 128 + wr * 64 + m * 16 + lk * 4 + j;
        if (row < cnt) {
          if (seg == 7) y[(size_t)row * 1024 + col] = acc[m][n][j];
          else          yr[(size_t)(obase + row) * 1024 + col] = acc[m][n][j];
        }
      }
    }
}

// ---------------- combine: y[m] += yr[tokrow[m]] ----------------
__global__ __launch_bounds__(256) void combine_kernel(const float* __restrict__ yr,
                                                      const int* __restrict__ tokrow,
                                                      float* __restrict__ y) {
  int m = blockIdx.x;
  int d = threadIdx.x * 4;
  int r = tokrow[m];
  float4 a = *reinterpret_cast<const float4*>(yr + (size_t)r * 1024 + d);
  float4 o = *reinterpret_cast<const float4*>(y + (size_t)m * 1024 + d);
  o.x += a.x; o.y += a.y; o.z += a.z; o.w += a.w;
  *reinterpret_cast<float4*>(y + (size_t)m * 1024 + d) = o;
}

extern "C" void kernel_launch(void* const* d_in, const int* in_sizes, int n_in,
                              void* d_out, int out_size, void* d_ws, size_t ws_size,
                              hipStream_t stream)
{
  const float* x   = (const float*)d_in[0];   // [2048][1024]
  const float* Wg  = (const float*)d_in[1];   // [1024][8]
  const float* Wl1 = (const float*)d_in[2];   // [8][1024][4096]
  const float* Wl2 = (const float*)d_in[3];   // [8][2048][1024]
  float* y = (float*)d_out;                   // [2048][1024]
  char* ws = (char*)d_ws;

  uint16_t* xbf = (uint16_t*)(ws);                    //  4 MiB
  uint16_t* h   = (uint16_t*)(ws + (4ull  << 20));    // 16 MiB
  float*    yr  = (float*)   (ws + (20ull << 20));    //  8 MiB
  int* idx    = (int*)(ws + (28ull << 20));
  int* tokrow = idx + 2048;
  int* soff   = tokrow + 2048;
  int* scnt   = soff + 8;
  int* rowmap = scnt + 8;  // 2048 ints

  gate_kernel<<<512, 256, 0, stream>>>(x, Wg, xbf, idx);
  compact_kernel<<<1, 256, 0, stream>>>(idx, soff, scnt, rowmap, tokrow);
  ffn1_kernel<<<dim3(32, 58), 256, 0, stream>>>(xbf, Wl1, soff, scnt, rowmap, h);
  ffn2_kernel<<<dim3(8, 58), 256, 0, stream>>>(h, Wl2, soff, scnt, y, yr);
  combine_kernel<<<2048, 256, 0, stream>>>(yr, tokrow, y);
}